// Round 1
// baseline (280.307 us; speedup 1.0000x reference)
//
#include <hip/hip_runtime.h>
#include <stdint.h>

// S6Layer on MI355X. B=8, L=4096, DM=256, DI=384, DS=8, CHUNK=32.
// Stages: cvt(w->bf16) -> LN -> GEMM1(+silu split) -> GEMM2(+softplus) -> scan -> GEMM3(+resid)
#define B_  8
#define L_  4096
#define DM  256
#define DI  384
#define DS  8
#define M_  (B_*L_)   // 32768 tokens

typedef float f32x4 __attribute__((ext_vector_type(4)));
typedef short s16x8 __attribute__((ext_vector_type(8)));

__device__ __forceinline__ unsigned short f2bf(float f) {
  union { float f; uint32_t u; } v; v.f = f;
  uint32_t r = v.u + 0x7FFFu + ((v.u >> 16) & 1u);   // RNE
  return (unsigned short)(r >> 16);
}
__device__ __forceinline__ float bf2f(unsigned short h) {
  union { uint32_t u; float f; } v; v.u = ((uint32_t)h) << 16;
  return v.f;
}
__device__ __forceinline__ float silu_f(float x) { return x / (1.f + __expf(-x)); }

// ---------------- weight fp32 -> bf16 ----------------
__global__ __launch_bounds__(256) void cvt_kernel(
    const float* __restrict__ w0, const float* __restrict__ w1, const float* __restrict__ w2,
    unsigned short* __restrict__ o0, unsigned short* __restrict__ o1, unsigned short* __restrict__ o2) {
  int i = blockIdx.x * 256 + threadIdx.x;
  if (i < 3*DI*DM) o0[i] = f2bf(w0[i]);
  if (i < DI*DI)   o1[i] = f2bf(w1[i]);
  if (i < DM*DI)   o2[i] = f2bf(w2[i]);
}

// ---------------- layernorm: one wave per token ----------------
__global__ __launch_bounds__(256) void ln_kernel(
    const float* __restrict__ x, const float* __restrict__ gamma, const float* __restrict__ beta,
    unsigned short* __restrict__ xn) {
  int token = blockIdx.x * 4 + (threadIdx.x >> 6);
  int lane  = threadIdx.x & 63;
  const float4 v = *(const float4*)(x + (size_t)token*DM + lane*4);
  float s  = v.x + v.y + v.z + v.w;
  float ss = v.x*v.x + v.y*v.y + v.z*v.z + v.w*v.w;
  #pragma unroll
  for (int off = 32; off > 0; off >>= 1) {
    s  += __shfl_xor(s,  off, 64);
    ss += __shfl_xor(ss, off, 64);
  }
  float mean = s * (1.f/DM);
  float var  = ss * (1.f/DM) - mean*mean;
  float rstd = rsqrtf(var + 1e-5f);
  const float4 g = *(const float4*)(gamma + lane*4);
  const float4 b = *(const float4*)(beta  + lane*4);
  ushort4 o;
  o.x = f2bf((v.x - mean)*rstd*g.x + b.x);
  o.y = f2bf((v.y - mean)*rstd*g.y + b.y);
  o.z = f2bf((v.z - mean)*rstd*g.z + b.z);
  o.w = f2bf((v.w - mean)*rstd*g.w + b.w);
  *(ushort4*)(xn + (size_t)token*DM + lane*4) = o;
}

// ---------------- bf16 MFMA GEMM: C[M,N] = A[M,K] @ Bw[N,K]^T (+ epilogue) ----------------
// 128x128 tile, BK=64, 256 threads (2x2 waves, 64x64 per wave, 4x4 of 16x16x32 MFMA).
// Staging via global_load_lds width=16; LDS 16B-chunk col XOR-swizzled with (row&7)
// so fragment ds_read_b128 lands at <=2-way bank aliasing (free per m136).
template<int EPI>
__global__ __launch_bounds__(256) void gemm_bt(
    const unsigned short* __restrict__ A,   // [M,K] bf16
    const unsigned short* __restrict__ Bw,  // [N,K] bf16 (weight rows = output cols)
    int K,
    const float* __restrict__ bias,         // [N]
    unsigned short* __restrict__ o_xp, unsigned short* __restrict__ o_z,
    unsigned short* __restrict__ o_dtin,    // EPI=1
    unsigned short* __restrict__ o_bf,      // EPI=2
    const float* __restrict__ resid, float* __restrict__ o_f)  // EPI=3
{
  __shared__ unsigned short sA[128*64];
  __shared__ unsigned short sB[128*64];
  const int t = threadIdx.x;
  const int mbase = blockIdx.x * 128;
  const int nbase = blockIdx.y * 128;

  // staging descriptors: chunk c = i*256+t, LDS holds global chunk (c&7)^(row&7) at slot c
  const unsigned short* gA[4]; const unsigned short* gB[4];
  int ldsc[4];
  #pragma unroll
  for (int i = 0; i < 4; ++i) {
    int c = i*256 + t;
    int row = c >> 3;
    int qs = (c & 7) ^ (row & 7);
    gA[i] = A  + (size_t)(mbase + row)*K + qs*8;
    gB[i] = Bw + (size_t)(nbase + row)*K + qs*8;
    ldsc[i] = c * 8;   // element offset (16B = 8 bf16)
  }

  const int lane = t & 63;
  const int w  = t >> 6;
  const int wm = (w & 1) * 64;
  const int wn = (w >> 1) * 64;
  const int fr = lane & 15;   // fragment row/col within 16
  const int fq = lane >> 4;   // quad

  f32x4 zero = {0.f, 0.f, 0.f, 0.f};
  f32x4 acc[4][4];
  #pragma unroll
  for (int mi = 0; mi < 4; ++mi)
    #pragma unroll
    for (int ni = 0; ni < 4; ++ni) acc[mi][ni] = zero;

  const int kiters = K >> 6;
  for (int kt = 0; kt < kiters; ++kt) {
    __syncthreads();
    #pragma unroll
    for (int i = 0; i < 4; ++i) {
      __builtin_amdgcn_global_load_lds(
          (__attribute__((address_space(1))) void*)gA[i],
          (__attribute__((address_space(3))) void*)(sA + ldsc[i]), 16, 0, 0);
      __builtin_amdgcn_global_load_lds(
          (__attribute__((address_space(1))) void*)gB[i],
          (__attribute__((address_space(3))) void*)(sB + ldsc[i]), 16, 0, 0);
      gA[i] += 64; gB[i] += 64;
    }
    __syncthreads();   // drains vmcnt before ds_read (m97 structure)
    #pragma unroll
    for (int h = 0; h < 2; ++h) {
      s16x8 af[4], bfr[4];
      #pragma unroll
      for (int mi = 0; mi < 4; ++mi) {
        int r  = wm + mi*16 + fr;
        int qs = (h*4 + fq) ^ (r & 7);
        af[mi] = *(const s16x8*)(sA + r*64 + qs*8);
      }
      #pragma unroll
      for (int ni = 0; ni < 4; ++ni) {
        int r  = wn + ni*16 + fr;
        int qs = (h*4 + fq) ^ (r & 7);
        bfr[ni] = *(const s16x8*)(sB + r*64 + qs*8);
      }
      #pragma unroll
      for (int mi = 0; mi < 4; ++mi)
        #pragma unroll
        for (int ni = 0; ni < 4; ++ni)
          acc[mi][ni] = __builtin_amdgcn_mfma_f32_16x16x32_bf16(af[mi], bfr[ni], acc[mi][ni], 0, 0, 0);
    }
  }

  // epilogue: lane holds C[row=fq*4+r][col=fr] per 16x16 tile (m89-verified layout)
  #pragma unroll
  for (int ni = 0; ni < 4; ++ni) {
    int gn = nbase + wn + ni*16 + fr;
    float bv = bias[gn];
    #pragma unroll
    for (int mi = 0; mi < 4; ++mi) {
      int gm0 = mbase + wm + mi*16 + fq*4;
      #pragma unroll
      for (int r = 0; r < 4; ++r) {
        float c = acc[mi][ni][r] + bv;
        size_t gm = (size_t)(gm0 + r);
        if constexpr (EPI == 1) {
          if (gn < DI)            o_xp[gm*DI + gn]          = f2bf(silu_f(c));
          else if (gn < 2*DI)     o_z[gm*DI + (gn - DI)]    = f2bf(silu_f(c));
          else                    o_dtin[gm*DI + (gn-2*DI)] = f2bf(c);
        } else if constexpr (EPI == 2) {
          float sp = (c > 20.f) ? c : log1pf(__expf(c));
          o_bf[gm*DI + gn] = f2bf(sp);
        } else {
          o_f[gm*DM + gn] = c + resid[gm*DM + gn];
        }
      }
    }
  }
}

// ---------------- chunked selective scan ----------------
// one thread per (chunk, channel); h resets to 0 each 32-step chunk (faithful to ref)
__global__ __launch_bounds__(384) void scan_kernel(
    const unsigned short* __restrict__ xp, const unsigned short* __restrict__ dt,
    const unsigned short* __restrict__ zb, const float* __restrict__ A_log,
    const float* __restrict__ D_vec, unsigned short* __restrict__ yz) {
  int g  = blockIdx.x;      // 0..(M_/32-1)
  int di = threadIdx.x;     // 0..383
  size_t base = (size_t)g * 32 * DI + di;
  float a[DS];
  #pragma unroll
  for (int s = 0; s < DS; ++s) a[s] = -__expf(A_log[di*DS + s]);   // A = -exp(A_log)
  float Dv = D_vec[di];
  float h[DS] = {0.f,0.f,0.f,0.f,0.f,0.f,0.f,0.f};
  for (int tt = 0; tt < 32; ++tt) {
    size_t idx = base + (size_t)tt * DI;
    float xv  = bf2f(xp[idx]);
    float dtv = bf2f(dt[idx]);
    float y = 0.f;
    #pragma unroll
    for (int s = 0; s < DS; ++s) {
      h[s] = h[s] * __expf(dtv * a[s]) + xv;
      y += h[s];
    }
    float zv = bf2f(zb[idx]);
    yz[idx] = f2bf(y * zv + xv * Dv);
  }
}

extern "C" void kernel_launch(void* const* d_in, const int* in_sizes, int n_in,
                              void* d_out, int out_size, void* d_ws, size_t ws_size,
                              hipStream_t stream) {
  const float* x     = (const float*)d_in[0];
  const float* gamma = (const float*)d_in[1];
  const float* beta  = (const float*)d_in[2];
  const float* W_in  = (const float*)d_in[3];
  const float* b_in  = (const float*)d_in[4];
  const float* W_dt  = (const float*)d_in[5];
  const float* b_dt  = (const float*)d_in[6];
  const float* A_log = (const float*)d_in[7];
  const float* D_vec = (const float*)d_in[8];
  const float* W_out = (const float*)d_in[9];
  const float* b_out = (const float*)d_in[10];
  float* out = (float*)d_out;

  char* ws = (char*)d_ws;
  size_t off = 0;
  auto alloc = [&](size_t bytes) -> char* {
    char* p = ws + off; off += (bytes + 255) & ~(size_t)255; return p;
  };
  unsigned short* xn    = (unsigned short*)alloc((size_t)M_*DM*2);  // 16.8 MB
  unsigned short* xpb   = (unsigned short*)alloc((size_t)M_*DI*2);  // 25.2 MB
  unsigned short* zb    = (unsigned short*)alloc((size_t)M_*DI*2);
  unsigned short* dtin  = (unsigned short*)alloc((size_t)M_*DI*2);
  unsigned short* dtb   = (unsigned short*)alloc((size_t)M_*DI*2);
  unsigned short* yzb   = dtin;   // dtin dead after GEMM2 -> reuse for yz
  unsigned short* winb  = (unsigned short*)alloc((size_t)3*DI*DM*2);
  unsigned short* wdtb  = (unsigned short*)alloc((size_t)DI*DI*2);
  unsigned short* woutb = (unsigned short*)alloc((size_t)DM*DI*2);

  cvt_kernel<<<dim3((3*DI*DM + 255)/256), 256, 0, stream>>>(W_in, W_dt, W_out, winb, wdtb, woutb);
  ln_kernel<<<dim3(M_/4), 256, 0, stream>>>(x, gamma, beta, xn);
  // GEMM1: xn[M,256] @ W_in[1152,256]^T ; split cols -> silu(xp), silu(z), dtin
  gemm_bt<1><<<dim3(M_/128, (3*DI)/128), 256, 0, stream>>>(
      xn, winb, DM, b_in, xpb, zb, dtin, nullptr, nullptr, nullptr);
  // GEMM2: dtin[M,384] @ W_dt[384,384]^T ; softplus -> dt
  gemm_bt<2><<<dim3(M_/128, DI/128), 256, 0, stream>>>(
      dtin, wdtb, DI, b_dt, nullptr, nullptr, nullptr, dtb, nullptr, nullptr);
  // scan -> yz = y*z + xp*D
  scan_kernel<<<dim3(M_/32), DI, 0, stream>>>(xpb, dtb, zb, A_log, D_vec, yzb);
  // GEMM3: yz[M,384] @ W_out[256,384]^T + b_out + residual -> out (fp32)
  gemm_bt<3><<<dim3(M_/128, DM/128), 256, 0, stream>>>(
      yzb, woutb, DI, b_out, nullptr, nullptr, nullptr, nullptr, x, out);
}